// Round 2
// baseline (482.887 us; speedup 1.0000x reference)
//
#include <hip/hip_runtime.h>
#include <math.h>

#define NN 131072
#define KK 27
#define FIN 3
#define FOUT 32
#define EPS 1e-5f

typedef _Float16 f16;
typedef f16 f16x8 __attribute__((ext_vector_type(8)));

// Phase 1: h = silu(bn1(einsum(x_feats[nbr_idx], w1))) -> d_ws [N,32] f16
// 4 threads per node; thread computes 8 outputs [p*8, p*8+8), p wave-uniform.
__global__ __launch_bounds__(256) void conv1_kernel(
    const float* __restrict__ x_feats,   // [N,3]
    const int*   __restrict__ nbr_idx,   // [N,27]
    const float* __restrict__ w1,        // [27,3,32]
    const float* __restrict__ g1,  const float* __restrict__ b1,
    const float* __restrict__ m1,  const float* __restrict__ v1,
    f16* __restrict__ h_out)             // [N,32] f16
{
    const int p  = blockIdx.x & 3;                    // wave-uniform out-group
    const int ob = p * 8;
    const int n  = (blockIdx.x >> 2) * 256 + threadIdx.x;

    float acc[8];
#pragma unroll
    for (int o = 0; o < 8; ++o) acc[o] = 0.f;

    const int* nb = nbr_idx + (size_t)n * KK;
#pragma unroll 3
    for (int k = 0; k < KK; ++k) {
        const int idx = nb[k];
        const float* xr = x_feats + (size_t)idx * FIN;
        const float x0 = xr[0], x1 = xr[1], x2 = xr[2];
        const float* w = w1 + k * FIN * FOUT + ob;    // wave-uniform -> s_load
#pragma unroll
        for (int o = 0; o < 8; ++o) {
            float a = acc[o];
            a = fmaf(x0, w[o],            a);
            a = fmaf(x1, w[FOUT + o],     a);
            a = fmaf(x2, w[2 * FOUT + o], a);
            acc[o] = a;
        }
    }

    f16x8 hv;
#pragma unroll
    for (int o = 0; o < 8; ++o) {
        const float sc = g1[ob + o] * rsqrtf(v1[ob + o] + EPS);
        float v = (acc[o] - m1[ob + o]) * sc + b1[ob + o];
        v = v / (1.f + __expf(-v));                   // silu
        hv[o] = (f16)v;
    }
    *(f16x8*)(h_out + (size_t)n * FOUT + ob) = hv;    // 16B store
}

// Phase 2: x_out = einsum(h[nbr_idx], w2); fused with point-branch MLP.
// 4 threads per node; thread computes 8 outputs, p wave-uniform.
__global__ __launch_bounds__(256) void conv2_kernel(
    const f16*   __restrict__ h,         // [N,32] f16
    const int*   __restrict__ nbr_idx,   // [N,27]
    const float* __restrict__ w2,        // [27,32,32]
    const float* __restrict__ z_feats,   // [N,3]
    const float* __restrict__ mlp_w,     // [3,32]
    const float* __restrict__ mlp_b,
    const float* __restrict__ mg, const float* __restrict__ mbeta,
    const float* __restrict__ mm, const float* __restrict__ mv,
    float* __restrict__ out)             // [2,N,32]
{
    const int p  = blockIdx.x & 3;                    // wave-uniform out-group
    const int ob = p * 8;
    const int n  = (blockIdx.x >> 2) * 256 + threadIdx.x;

    float acc[8];
#pragma unroll
    for (int o = 0; o < 8; ++o) acc[o] = 0.f;

    const int* nb = nbr_idx + (size_t)n * KK;
#pragma unroll 3
    for (int k = 0; k < KK; ++k) {
        const int idx = nb[k];
        const f16x8* hr = (const f16x8*)(h + (size_t)idx * FOUT);  // 64B row
        const f16x8 r0 = hr[0], r1 = hr[1], r2 = hr[2], r3 = hr[3];
        const float* w = w2 + k * FOUT * FOUT + ob;   // wave-uniform -> s_load
#pragma unroll
        for (int i = 0; i < 8; ++i) {
            const float hv = (float)r0[i];
            const float* wr = w + i * FOUT;
#pragma unroll
            for (int o = 0; o < 8; ++o) acc[o] = fmaf(hv, wr[o], acc[o]);
        }
#pragma unroll
        for (int i = 0; i < 8; ++i) {
            const float hv = (float)r1[i];
            const float* wr = w + (8 + i) * FOUT;
#pragma unroll
            for (int o = 0; o < 8; ++o) acc[o] = fmaf(hv, wr[o], acc[o]);
        }
#pragma unroll
        for (int i = 0; i < 8; ++i) {
            const float hv = (float)r2[i];
            const float* wr = w + (16 + i) * FOUT;
#pragma unroll
            for (int o = 0; o < 8; ++o) acc[o] = fmaf(hv, wr[o], acc[o]);
        }
#pragma unroll
        for (int i = 0; i < 8; ++i) {
            const float hv = (float)r3[i];
            const float* wr = w + (24 + i) * FOUT;
#pragma unroll
            for (int o = 0; o < 8; ++o) acc[o] = fmaf(hv, wr[o], acc[o]);
        }
    }

    // point branch (8 outputs of this thread's group)
    const float z0 = z_feats[(size_t)n * 3 + 0];
    const float z1 = z_feats[(size_t)n * 3 + 1];
    const float z2 = z_feats[(size_t)n * 3 + 2];

    float* o0 = out + (size_t)n * FOUT + ob;
    float* o1 = out + (size_t)NN * FOUT + (size_t)n * FOUT + ob;
#pragma unroll
    for (int o = 0; o < 8; ++o) {
        float z = mlp_b[ob + o];
        z = fmaf(z0, mlp_w[ob + o],            z);
        z = fmaf(z1, mlp_w[FOUT + ob + o],     z);
        z = fmaf(z2, mlp_w[2 * FOUT + ob + o], z);
        const float sc = mg[ob + o] * rsqrtf(mv[ob + o] + EPS);
        z = (z - mm[ob + o]) * sc + mbeta[ob + o];
        z = fmaxf(z, 0.f);
        const float v = acc[o] + z;
        o0[o] = v;
        o1[o] = v;
    }
}

extern "C" void kernel_launch(void* const* d_in, const int* in_sizes, int n_in,
                              void* d_out, int out_size, void* d_ws, size_t ws_size,
                              hipStream_t stream) {
    const float* x_feats = (const float*)d_in[0];
    const float* z_feats = (const float*)d_in[1];
    const int*   nbr_idx = (const int*)d_in[2];
    const float* w1      = (const float*)d_in[3];
    const float* bn1_g   = (const float*)d_in[4];
    const float* bn1_b   = (const float*)d_in[5];
    const float* bn1_m   = (const float*)d_in[6];
    const float* bn1_v   = (const float*)d_in[7];
    const float* w2      = (const float*)d_in[8];
    const float* mlp_w   = (const float*)d_in[9];
    const float* mlp_b   = (const float*)d_in[10];
    const float* mlp_g   = (const float*)d_in[11];
    const float* mlp_be  = (const float*)d_in[12];
    const float* mlp_m   = (const float*)d_in[13];
    const float* mlp_v   = (const float*)d_in[14];

    f16* h = (f16*)d_ws;                 // N*32 f16 = 8 MiB scratch
    float* out = (float*)d_out;

    dim3 block(256);
    dim3 grid(NN * 4 / 256);             // 4 threads per node

    conv1_kernel<<<grid, block, 0, stream>>>(x_feats, nbr_idx, w1,
                                             bn1_g, bn1_b, bn1_m, bn1_v, h);
    conv2_kernel<<<grid, block, 0, stream>>>(h, nbr_idx, w2, z_feats,
                                             mlp_w, mlp_b, mlp_g, mlp_be,
                                             mlp_m, mlp_v, out);
}

// Round 3
// 167.488 us; speedup vs baseline: 2.8831x; 2.8831x over previous
//
#include <hip/hip_runtime.h>
#include <math.h>

#define NN 131072
#define KK 27
#define FIN 3
#define FOUT 32
#define EPS 1e-5f

typedef _Float16 f16;
typedef __attribute__((ext_vector_type(8))) _Float16 f16x8;
typedef __attribute__((ext_vector_type(16))) float f32x16;

// ---------------------------------------------------------------------------
// Pack w2 (f32 [27][32][32]) into f16 MFMA B-operand fragments:
// w2p[k][half][lane][j]  (half = which 16 of the 32 input-features)
// B layout for v_mfma_f32_32x32x16: col = lane&31, kdim = (lane>>5)*8 + j
// ---------------------------------------------------------------------------
__global__ __launch_bounds__(256) void pack_w2_kernel(
    const float* __restrict__ w2, f16* __restrict__ w2p)
{
    const int t = blockIdx.x * 256 + threadIdx.x;
    if (t >= KK * 2 * 64 * 8) return;
    const int k    = t >> 10;          // 1024 elems per spatial k
    const int rem  = t & 1023;
    const int half = rem >> 9;
    const int l    = (rem >> 3) & 63;
    const int j    = rem & 7;
    const int krow = half * 16 + ((l >> 5) << 3) + j;  // input-feature row
    const int n    = l & 31;                           // output column
    w2p[t] = (f16)w2[k * (FOUT * FOUT) + krow * FOUT + n];
}

// ---------------------------------------------------------------------------
// Phase 1: h = silu(bn1(einsum(x_feats[nbr_idx], w1))) -> [N,32] f16
// 1 thread per node (no gather duplication). All 27 idx hoisted first.
// ---------------------------------------------------------------------------
__global__ __launch_bounds__(256) void conv1_kernel(
    const float* __restrict__ x_feats,   // [N,3]
    const int*   __restrict__ nbr_idx,   // [N,27]
    const float* __restrict__ w1,        // [27,3,32]
    const float* __restrict__ g1,  const float* __restrict__ b1,
    const float* __restrict__ m1,  const float* __restrict__ v1,
    f16* __restrict__ h_out)             // [N,32] f16
{
    const int n = blockIdx.x * 256 + threadIdx.x;

    int idxs[KK];
    const int* nb = nbr_idx + (size_t)n * KK;
#pragma unroll
    for (int k = 0; k < KK; ++k) idxs[k] = nb[k];   // break idx->gather chain

    float acc[FOUT];
#pragma unroll
    for (int o = 0; o < FOUT; ++o) acc[o] = 0.f;

#pragma unroll
    for (int c = 0; c < 3; ++c) {                   // 3 chunks of 9 neighbors
        float xs[9][3];
#pragma unroll
        for (int q = 0; q < 9; ++q) {               // 27 loads in flight
            const float* xr = x_feats + (size_t)idxs[c * 9 + q] * FIN;
            xs[q][0] = xr[0]; xs[q][1] = xr[1]; xs[q][2] = xr[2];
        }
#pragma unroll
        for (int q = 0; q < 9; ++q) {
            const float* w = w1 + (c * 9 + q) * (FIN * FOUT); // uniform->s_load
#pragma unroll
            for (int o = 0; o < FOUT; ++o) {
                float a = acc[o];
                a = fmaf(xs[q][0], w[o],            a);
                a = fmaf(xs[q][1], w[FOUT + o],     a);
                a = fmaf(xs[q][2], w[2 * FOUT + o], a);
                acc[o] = a;
            }
        }
    }

    f16* hr = h_out + (size_t)n * FOUT;
#pragma unroll
    for (int g = 0; g < 4; ++g) {
        f16x8 hv;
#pragma unroll
        for (int j = 0; j < 8; ++j) {
            const int o = g * 8 + j;
            const float sc = g1[o] * rsqrtf(v1[o] + EPS);
            float v = (acc[o] - m1[o]) * sc + b1[o];
            v = v / (1.f + __expf(-v));              // silu
            hv[j] = (f16)v;
        }
        *(f16x8*)(hr + g * 8) = hv;                  // 16B stores
    }
}

// ---------------------------------------------------------------------------
// Phase 2 (MFMA): x_out = einsum(h[nbr_idx], w2) via v_mfma_f32_32x32x16_f16.
// One wave = 32 nodes. Per spatial k: gathered A-tile (each lane one disjoint
// 16B chunk -> zero duplication) x packed B-frag, 2 MFMA (K=32 split 16+16).
// Point-branch MLP+BN+ReLU fused in epilogue; result written to both outputs.
// ---------------------------------------------------------------------------
__global__ __launch_bounds__(256) void conv2_mfma_kernel(
    const f16*   __restrict__ h,         // [N,32] f16
    const int*   __restrict__ nbr_idx,   // [N,27]
    const f16*   __restrict__ w2p,       // packed [27][2][64][8] f16
    const float* __restrict__ z_feats,   // [N,3]
    const float* __restrict__ mlp_w,     // [3,32]
    const float* __restrict__ mlp_b,
    const float* __restrict__ mg, const float* __restrict__ mbe,
    const float* __restrict__ mm, const float* __restrict__ mv,
    float* __restrict__ out)             // [2,N,32]
{
    const int lane = threadIdx.x & 63;
    const int wave = threadIdx.x >> 6;
    const int base = (blockIdx.x * 4 + wave) * 32;   // this wave's node base
    const int row  = lane & 31;                      // A row / out row group
    const int hi   = lane >> 5;                      // which k-half of 8

    // hoist all 27 neighbor indices for this lane's row
    int idxs[KK];
    const int* nb = nbr_idx + (size_t)(base + row) * KK;
#pragma unroll
    for (int k = 0; k < KK; ++k) idxs[k] = nb[k];

    f32x16 acc = {};                                 // zero accumulator

    const f16x8* bp = (const f16x8*)w2p;             // [k*128 + half*64 + lane]
#pragma unroll 3
    for (int k = 0; k < KK; ++k) {
        const f16* hr = h + (size_t)idxs[k] * FOUT + hi * 8;
        const f16x8 a1 = *(const f16x8*)hr;          // feats [0..16) half
        const f16x8 a2 = *(const f16x8*)(hr + 16);   // feats [16..32) half
        const f16x8 b1 = bp[k * 128 + lane];
        const f16x8 b2 = bp[k * 128 + 64 + lane];
        acc = __builtin_amdgcn_mfma_f32_32x32x16_f16(a1, b1, acc, 0, 0, 0);
        acc = __builtin_amdgcn_mfma_f32_32x32x16_f16(a2, b2, acc, 0, 0, 0);
    }

    // ---- epilogue: point branch for output column n0, fused add + store ----
    const int n0 = lane & 31;
    const float wc0 = mlp_w[n0];
    const float wc1 = mlp_w[FOUT + n0];
    const float wc2 = mlp_w[2 * FOUT + n0];
    const float sc  = mg[n0] * rsqrtf(mv[n0] + EPS);
    const float bi  = mlp_b[n0];
    const float mmv = mm[n0];
    const float mbv = mbe[n0];

#pragma unroll
    for (int r = 0; r < 16; ++r) {
        const int m    = (r & 3) + ((r >> 2) << 3) + (hi << 2); // C/D row map
        const int node = base + m;
        const float* zr = z_feats + (size_t)node * FIN;
        float z = bi;
        z = fmaf(zr[0], wc0, z);
        z = fmaf(zr[1], wc1, z);
        z = fmaf(zr[2], wc2, z);
        z = (z - mmv) * sc + mbv;
        z = fmaxf(z, 0.f);
        const float v = acc[r] + z;
        out[(size_t)node * FOUT + n0] = v;
        out[(size_t)NN * FOUT + (size_t)node * FOUT + n0] = v;
    }
}

extern "C" void kernel_launch(void* const* d_in, const int* in_sizes, int n_in,
                              void* d_out, int out_size, void* d_ws, size_t ws_size,
                              hipStream_t stream) {
    const float* x_feats = (const float*)d_in[0];
    const float* z_feats = (const float*)d_in[1];
    const int*   nbr_idx = (const int*)d_in[2];
    const float* w1      = (const float*)d_in[3];
    const float* bn1_g   = (const float*)d_in[4];
    const float* bn1_b   = (const float*)d_in[5];
    const float* bn1_m   = (const float*)d_in[6];
    const float* bn1_v   = (const float*)d_in[7];
    const float* w2      = (const float*)d_in[8];
    const float* mlp_w   = (const float*)d_in[9];
    const float* mlp_b   = (const float*)d_in[10];
    const float* mlp_g   = (const float*)d_in[11];
    const float* mlp_be  = (const float*)d_in[12];
    const float* mlp_m   = (const float*)d_in[13];
    const float* mlp_v   = (const float*)d_in[14];

    f16* h   = (f16*)d_ws;                                   // 8 MiB
    f16* w2p = (f16*)((char*)d_ws + (size_t)8 * 1024 * 1024); // 54 KiB packed
    float* out = (float*)d_out;

    pack_w2_kernel<<<(KK * 1024 + 255) / 256, 256, 0, stream>>>(w2, w2p);
    conv1_kernel<<<NN / 256, 256, 0, stream>>>(x_feats, nbr_idx, w1,
                                               bn1_g, bn1_b, bn1_m, bn1_v, h);
    conv2_mfma_kernel<<<NN / 128, 256, 0, stream>>>(h, nbr_idx, w2p, z_feats,
                                                    mlp_w, mlp_b, mlp_g, mlp_be,
                                                    mlp_m, mlp_v, out);
}